// Round 2
// baseline (597.082 us; speedup 1.0000x reference)
//
#include <hip/hip_runtime.h>

// AssociationLayer: masked Sinkhorn (100 iters) + mutual-argmax assignment.
// R8: R7's MFMA loop + coalesced LDS-staged epilogue.
//  R7 post-mortem: WRITE_SIZE 414 MB vs 135 MB ideal (3.1x RMW amplification
//  from scattered scalar interior stores; 16 rows per store instr -> partial
//  cachelines evicted + refetched). Loop itself is fast (~16 MFMA/iter).
//  R8 epilogue: 16-row chunks, double-buffered LDS pipeline:
//   - phase c: owner wave (c>>1, half c&1) recomputes T from K frags ->
//     Tbuf[c&1][16][260] (b128 writes, bank-uniform), computes row-has bits;
//     ALL waves simultaneously copy chunk c-1: thread (tid>>5, tid&31) writes
//     cols 4tp..4tp+3 of its row -> consecutive tids = consecutive addresses,
//     every 64B line fully written within 4 adjacent store instrs.
//   - copier recomputes A = (T==rm_s[row] && T==cm_s[col]) from staged T
//     (bitwise-identical), and writes deaths col (nd) -> dense exact coverage
//     of [0, nt*stride). births row / corner / zero-fill unchanged.
//  Runtime half-index (c&1) dispatched via compile-time lambda args so the
//  KA/rm register arrays are never runtime-indexed (no scratch).

#define T_MAX   256
#define L_FLAT  (257 * 257)
#define N_ITERS 100
#define LAMBDA_F 10.0f
#define EPS_F    1e-12f
#define TBP     260    // Tbuf row stride (floats): %4==0 for b128, 260%32=4

#define ROR1 0x121
#define ROR2 0x122
#define ROR4 0x124
#define ROR8 0x128

typedef short bf8   __attribute__((ext_vector_type(8)));  // 8 bf16 = 4 VGPRs
typedef float f32x4 __attribute__((ext_vector_type(4)));

template<int CTRL>
__device__ __forceinline__ float dpp_addf(float x) {
    int t = __builtin_amdgcn_update_dpp(0, __float_as_int(x), CTRL, 0xF, 0xF, true);
    return x + __int_as_float(t);
}
__device__ __forceinline__ float swz16_addf(float x) {
    return x + __int_as_float(__builtin_amdgcn_ds_swizzle(__float_as_int(x), 0x401F));
}
__device__ __forceinline__ float swz16_maxf(float x) {
    return fmaxf(x, __int_as_float(__builtin_amdgcn_ds_swizzle(__float_as_int(x), 0x401F)));
}
__device__ __forceinline__ int swz16_ori(int x) {
    return x | __builtin_amdgcn_ds_swizzle(x, 0x401F);
}
__device__ __forceinline__ float fast_rcp(float x) {
#if __has_builtin(__builtin_amdgcn_rcpf)
    return __builtin_amdgcn_rcpf(x);
#else
    return 1.0f / x;
#endif
}
__device__ __forceinline__ unsigned short f2bf(float x) {   // RNE f32->bf16
    unsigned u = __float_as_uint(x);
    return (unsigned short)((u + 0x7FFFu + ((u >> 16) & 1u)) >> 16);
}
__device__ __forceinline__ float bf2f(short s) {            // exact bf16->f32
    return __uint_as_float(((unsigned)(unsigned short)s) << 16);
}

__global__ __launch_bounds__(512, 2) void assoc_sinkhorn_kernel(
    const float* __restrict__ aff,
    const int*   __restrict__ ndet,
    const int*   __restrict__ ntrk,
    float*       __restrict__ out_t,
    float*       __restrict__ out_a)
{
    const int b   = blockIdx.x;
    const int nd  = ndet[b];
    const int nt  = ntrk[b];
    const int tid = threadIdx.x;
    const int w   = tid >> 6;     // wave 0..7
    const int l   = tid & 63;
    const int lr  = l & 15;       // m/n index within 16x16 tile
    const int lk  = l >> 4;       // k-group 0..3

    __shared__ __align__(16) unsigned short u_bf[256];
    __shared__ __align__(16) unsigned short v_bf[256];
    __shared__ __align__(16) float u_f[256];
    __shared__ __align__(16) float v_f[256];
    __shared__ __align__(16) float supart[8];
    __shared__ __align__(16) float svpart[8];
    __shared__ __align__(16) float rm_s[256];
    __shared__ __align__(16) float cm_s[256];
    __shared__ __align__(16) float Tbuf[2][16][TBP];   // 33.3 KB staging
    __shared__ int rh_s[2][16];

    const float ndf = (float)nd;
    const float ntf = (float)nt;

    // ---------------- prologue: build bf16 K fragments ----------------
    bf8 KA[2][8];   // row-panel (A-operand layout)
    bf8 KB[2][8];   // col-panel (B-operand layout)
    const float* Ab = aff + (size_t)b * (T_MAX * T_MAX);

    #pragma unroll
    for (int a = 0; a < 2; ++a) {
        const int row = 32 * w + 16 * a + lr;
        const bool rv = (row < nt);
        const float* rp = Ab + (size_t)row * T_MAX;
        #pragma unroll
        for (int t = 0; t < 8; ++t) {
            const int c0 = 32 * t + 8 * lk;
            const float4 x0 = *reinterpret_cast<const float4*>(rp + c0);
            const float4 x1 = *reinterpret_cast<const float4*>(rp + c0 + 4);
            const float e[8] = {x0.x, x0.y, x0.z, x0.w, x1.x, x1.y, x1.z, x1.w};
            bf8 kk;
            #pragma unroll
            for (int j = 0; j < 8; ++j) {
                const float val = (rv && (c0 + j) < nd) ? __expf(LAMBDA_F * e[j]) : 0.0f;
                kk[j] = (short)f2bf(val);
            }
            KA[a][t] = kk;
        }
    }
    #pragma unroll
    for (int c = 0; c < 2; ++c) {
        const int col = 32 * w + 16 * c + lr;
        const bool cv = (col < nd);
        #pragma unroll
        for (int t = 0; t < 8; ++t) {
            const int r0 = 32 * t + 8 * lk;
            bf8 kk;
            #pragma unroll
            for (int j = 0; j < 8; ++j) {
                const float x = Ab[(size_t)(r0 + j) * T_MAX + col];
                const float val = (cv && (r0 + j) < nt) ? __expf(LAMBDA_F * x) : 0.0f;
                kk[j] = (short)f2bf(val);
            }
            KB[c][t] = kk;
        }
    }

    if (tid < 256) {
        v_bf[tid] = (tid < nd) ? f2bf(1.0f) : (unsigned short)0;
        v_f[tid]  = (tid < nd) ? 1.0f : 0.0f;
    }
    __syncthreads();

    float Sv  = ndf;    // sum of v over valid cols (wave-uniform)
    float vbd = 1.0f;   // v[nd]
    float ubd = 0.0f;   // u[nt]

    const int r_a0 = 32 * w + 4 * lk;   // base row of acc0 quad (a=0)

    // ---------------- Sinkhorn iterations ----------------
    for (int it = 0; it < N_ITERS; ++it) {
        // ---- dir1: p = K @ v  (row-panel, fully in-wave) ----
        bf8 VF[8];
        #pragma unroll
        for (int t = 0; t < 8; ++t)
            VF[t] = *reinterpret_cast<const bf8*>(&v_bf[32 * t + 8 * lk]);

        f32x4 acc0 = {0.0f, 0.0f, 0.0f, 0.0f};
        f32x4 acc1 = {0.0f, 0.0f, 0.0f, 0.0f};
        #pragma unroll
        for (int t = 0; t < 8; ++t) {
            acc0 = __builtin_amdgcn_mfma_f32_16x16x32_bf16(KA[0][t], VF[t], acc0, 0, 0, 0);
            acc1 = __builtin_amdgcn_mfma_f32_16x16x32_bf16(KA[1][t], VF[t], acc1, 0, 0, 0);
        }

        const float ubd_new = ndf * fast_rcp(Sv + vbd + EPS_F);
        const float vbdE = vbd + EPS_F;
        float u8[8];
        #pragma unroll
        for (int q = 0; q < 4; ++q) {
            u8[q]     = ((r_a0 + q)      < nt) ? fast_rcp(acc0[q] + vbdE) : 0.0f;
            u8[4 + q] = ((r_a0 + 16 + q) < nt) ? fast_rcp(acc1[q] + vbdE) : 0.0f;
        }

        // per-wave Sigma(u): values vary over lk only (redundant over lr)
        {
            float su = ((u8[0] + u8[1]) + (u8[2] + u8[3]))
                     + ((u8[4] + u8[5]) + (u8[6] + u8[7]));
            su = swz16_addf(su);
            su += __shfl_xor(su, 32, 64);
            if (l == 0) supart[w] = su;
        }

        // publish u (bf16 for MFMA, f32 for epilogue); writers: lr==0
        if (lr == 0) {
            const unsigned p01 = (unsigned)f2bf(u8[0]) | ((unsigned)f2bf(u8[1]) << 16);
            const unsigned p23 = (unsigned)f2bf(u8[2]) | ((unsigned)f2bf(u8[3]) << 16);
            const unsigned p45 = (unsigned)f2bf(u8[4]) | ((unsigned)f2bf(u8[5]) << 16);
            const unsigned p67 = (unsigned)f2bf(u8[6]) | ((unsigned)f2bf(u8[7]) << 16);
            *reinterpret_cast<uint2*>(&u_bf[r_a0])      = uint2{p01, p23};
            *reinterpret_cast<uint2*>(&u_bf[r_a0 + 16]) = uint2{p45, p67};
            f32x4 uf0 = {u8[0], u8[1], u8[2], u8[3]};
            f32x4 uf1 = {u8[4], u8[5], u8[6], u8[7]};
            *reinterpret_cast<f32x4*>(&u_f[r_a0])      = uf0;
            *reinterpret_cast<f32x4*>(&u_f[r_a0 + 16]) = uf1;
        }
        __syncthreads();   // barrier A: u published

        // ---- dir2: q = K^T @ u  (col-panel, fully in-wave) ----
        bf8 UF[8];
        #pragma unroll
        for (int t = 0; t < 8; ++t)
            UF[t] = *reinterpret_cast<const bf8*>(&u_bf[32 * t + 8 * lk]);

        f32x4 qa0 = {0.0f, 0.0f, 0.0f, 0.0f};
        f32x4 qa1 = {0.0f, 0.0f, 0.0f, 0.0f};
        #pragma unroll
        for (int t = 0; t < 8; ++t) {
            qa0 = __builtin_amdgcn_mfma_f32_16x16x32_bf16(UF[t], KB[0][t], qa0, 0, 0, 0);
            qa1 = __builtin_amdgcn_mfma_f32_16x16x32_bf16(UF[t], KB[1][t], qa1, 0, 0, 0);
        }

        // Su and vbd update (redundant per wave; supart covered by barrier A)
        const f32x4 sp0 = *reinterpret_cast<const f32x4*>(&supart[0]);
        const f32x4 sp1 = *reinterpret_cast<const f32x4*>(&supart[4]);
        const float Su = ((sp0[0] + sp0[1]) + (sp0[2] + sp0[3]))
                       + ((sp1[0] + sp1[1]) + (sp1[2] + sp1[3]));
        const float vbd_new = ntf * fast_rcp(Su + ubd_new + EPS_F);

        const float ubdE = ubd_new + EPS_F;
        const int c0i = 32 * w + lr;
        const int c1i = 32 * w + 16 + lr;
        const float v0 = (c0i < nd) ? fast_rcp(qa0[0] + ubdE) : 0.0f;
        const float v1 = (c1i < nd) ? fast_rcp(qa1[0] + ubdE) : 0.0f;

        // per-wave Sigma(v): values vary over lr only -> all-DPP row reduce
        {
            float sv = v0 + v1;
            sv = dpp_addf<ROR1>(sv);
            sv = dpp_addf<ROR2>(sv);
            sv = dpp_addf<ROR4>(sv);
            sv = dpp_addf<ROR8>(sv);
            if (l == 0) svpart[w] = sv;
        }
        if (lk == 0) {
            v_bf[c0i] = f2bf(v0);
            v_bf[c1i] = f2bf(v1);
            v_f[c0i]  = v0;
            v_f[c1i]  = v1;
        }
        ubd = ubd_new;
        vbd = vbd_new;
        __syncthreads();   // barrier B: v published

        const f32x4 vp0 = *reinterpret_cast<const f32x4*>(&svpart[0]);
        const f32x4 vp1 = *reinterpret_cast<const f32x4*>(&svpart[4]);
        Sv = ((vp0[0] + vp0[1]) + (vp0[2] + vp0[3]))
           + ((vp1[0] + vp1[1]) + (vp1[2] + vp1[3]));
    }

    // ================= epilogue =================
    // E1: rowmax on row-panel, colmax on col-panel. T = (u*k)*v, identical
    // mul order everywhere -> bitwise-consistent equality tests.
    float rm[2];
    #pragma unroll
    for (int a = 0; a < 2; ++a) {
        const int row = 32 * w + 16 * a + lr;
        const float ur = u_f[row];
        float mm = 0.0f;
        #pragma unroll
        for (int t = 0; t < 8; ++t) {
            const f32x4 va = *reinterpret_cast<const f32x4*>(&v_f[32 * t + 8 * lk]);
            const f32x4 vb = *reinterpret_cast<const f32x4*>(&v_f[32 * t + 8 * lk + 4]);
            const float vj[8] = {va[0], va[1], va[2], va[3], vb[0], vb[1], vb[2], vb[3]};
            #pragma unroll
            for (int j = 0; j < 8; ++j) {
                const float tv = ur * bf2f(KA[a][t][j]) * vj[j];
                mm = fmaxf(mm, tv);
            }
        }
        mm = swz16_maxf(mm);
        mm = fmaxf(mm, __shfl_xor(mm, 32, 64));
        rm[a] = mm;
        if (lk == 0) rm_s[row] = mm;
    }
    float cmv[2];
    #pragma unroll
    for (int c = 0; c < 2; ++c) {
        const int col = 32 * w + 16 * c + lr;
        const float vc = v_f[col];
        float mm = 0.0f;
        #pragma unroll
        for (int t = 0; t < 8; ++t) {
            const f32x4 ua = *reinterpret_cast<const f32x4*>(&u_f[32 * t + 8 * lk]);
            const f32x4 ub = *reinterpret_cast<const f32x4*>(&u_f[32 * t + 8 * lk + 4]);
            const float uj[8] = {ua[0], ua[1], ua[2], ua[3], ub[0], ub[1], ub[2], ub[3]};
            #pragma unroll
            for (int j = 0; j < 8; ++j) {
                const float tv = uj[j] * bf2f(KB[c][t][j]) * vc;
                mm = fmaxf(mm, tv);
            }
        }
        mm = swz16_maxf(mm);
        mm = fmaxf(mm, __shfl_xor(mm, 32, 64));
        cmv[c] = mm;
        if (lk == 0) cm_s[col] = mm;
    }
    __syncthreads();   // rm_s / cm_s published

    float* Ot = out_t + (size_t)b * L_FLAT;
    float* Oa = out_a + (size_t)b * L_FLAT;
    const int stride = nd + 1;

    // births row (col-panel: col-has + write) + corner
    #pragma unroll
    for (int c = 0; c < 2; ++c) {
        const int col = 32 * w + 16 * c + lr;
        const float vc = v_f[col];
        const float cmc = cmv[c];
        const bool cv = (col < nd);
        int has = 0;
        #pragma unroll
        for (int t = 0; t < 8; ++t) {
            const int rb = 32 * t + 8 * lk;
            const f32x4 ua = *reinterpret_cast<const f32x4*>(&u_f[rb]);
            const f32x4 ub = *reinterpret_cast<const f32x4*>(&u_f[rb + 4]);
            const f32x4 ra = *reinterpret_cast<const f32x4*>(&rm_s[rb]);
            const f32x4 rb4 = *reinterpret_cast<const f32x4*>(&rm_s[rb + 4]);
            const float uj[8] = {ua[0], ua[1], ua[2], ua[3], ub[0], ub[1], ub[2], ub[3]};
            const float rj[8] = {ra[0], ra[1], ra[2], ra[3], rb4[0], rb4[1], rb4[2], rb4[3]};
            #pragma unroll
            for (int j = 0; j < 8; ++j) {
                const int rowj = rb + j;
                const float tv = uj[j] * bf2f(KB[c][t][j]) * vc;
                const bool bit = (rowj < nt) && cv && (tv == rj[j]) && (tv == cmc);
                has |= bit ? 1 : 0;
            }
        }
        has = swz16_ori(has);
        has |= __shfl_xor(has, 32, 64);
        if (lk == 0 && cv) {
            const int kk = nt * stride + col;
            Ot[kk] = ubd * vc;
            Oa[kk] = has ? 0.0f : 1.0f;
        }
    }
    if (tid == 0) {
        const int kk = nt * stride + nd;
        Ot[kk] = ubd * vbd;
        Oa[kk] = 0.0f;
    }

    // ---- chunked interior + deaths: produce(c) || copy(c-1), dbuf ----
    // produce half-panel with compile-time register indices (no scratch)
    auto produce_half = [&](const bf8 (&KR)[8], const float rma, const int buf) {
        const int rowg = (buf == 0) ? 0 : 0;  // placeholder (row from caller ctx)
        (void)rowg;
        return;
    };
    (void)produce_half;

    const int nchunks = (nt + 15) >> 4;
    for (int c = 0; c <= nchunks; ++c) {
        if (c < nchunks && w == (c >> 1)) {
            const int buf = c & 1;
            const float ur = u_f[16 * c + lr];
            // compile-time dispatch over the half index (c&1)
            auto prod = [&](const bf8 (&KR)[8], const float rma) {
                int has = 0;
                #pragma unroll
                for (int t = 0; t < 8; ++t) {
                    const int cb = 32 * t + 8 * lk;
                    const f32x4 va  = *reinterpret_cast<const f32x4*>(&v_f[cb]);
                    const f32x4 vb  = *reinterpret_cast<const f32x4*>(&v_f[cb + 4]);
                    const f32x4 ca  = *reinterpret_cast<const f32x4*>(&cm_s[cb]);
                    const f32x4 cb4 = *reinterpret_cast<const f32x4*>(&cm_s[cb + 4]);
                    f32x4 o0, o1;
                    #pragma unroll
                    for (int j = 0; j < 4; ++j) {
                        const float tv = ur * bf2f(KR[t][j]) * va[j];
                        o0[j] = tv;
                        if ((cb + j) < nd && tv == rma && tv == ca[j]) has = 1;
                    }
                    #pragma unroll
                    for (int j = 0; j < 4; ++j) {
                        const float tv = ur * bf2f(KR[t][4 + j]) * vb[j];
                        o1[j] = tv;
                        if ((cb + 4 + j) < nd && tv == rma && tv == cb4[j]) has = 1;
                    }
                    *reinterpret_cast<f32x4*>(&Tbuf[buf][lr][cb])     = o0;
                    *reinterpret_cast<f32x4*>(&Tbuf[buf][lr][cb + 4]) = o1;
                }
                has = swz16_ori(has);
                has |= __shfl_xor(has, 32, 64);
                if (l < 16) rh_s[buf][lr] = has;
            };
            if ((c & 1) == 0) prod(KA[0], rm[0]);
            else              prod(KA[1], rm[1]);
        }
        if (c > 0) {
            const int cc  = c - 1;
            const int buf = cc & 1;
            const int rl  = tid >> 5;      // 0..15
            const int tp  = tid & 31;      // 0..31
            const int row = 16 * cc + rl;
            if (row < nt) {
                float* OtR = Ot + (size_t)row * stride;
                float* OaR = Oa + (size_t)row * stride;
                const float rmr = rm_s[row];
                #pragma unroll
                for (int k2 = 0; k2 < 2; ++k2) {
                    const int c0 = 4 * tp + 128 * k2;
                    const f32x4 tv4 = *reinterpret_cast<const f32x4*>(&Tbuf[buf][rl][c0]);
                    const f32x4 cm4 = *reinterpret_cast<const f32x4*>(&cm_s[c0]);
                    #pragma unroll
                    for (int j = 0; j < 4; ++j) {
                        const int col = c0 + j;
                        if (col < nd) {
                            const float tv = tv4[j];
                            OtR[col] = tv;
                            OaR[col] = (tv == rmr && tv == cm4[j]) ? 1.0f : 0.0f;
                        }
                    }
                }
                if (tp == 0) {
                    OtR[nd] = u_f[row] * vbd;
                    OaR[nd] = rh_s[buf][rl] ? 0.0f : 1.0f;
                }
            }
        }
        __syncthreads();
    }

    // zero-fill padding [length, L_FLAT)
    const int length = (nt + 1) * stride;
    for (int k = length + tid; k < L_FLAT; k += 512) {
        Ot[k] = 0.0f;
        Oa[k] = 0.0f;
    }
}

extern "C" void kernel_launch(void* const* d_in, const int* in_sizes, int n_in,
                              void* d_out, int out_size, void* d_ws, size_t ws_size,
                              hipStream_t stream)
{
    const float* aff  = (const float*)d_in[0];
    const int*   ndet = (const int*)d_in[1];
    const int*   ntrk = (const int*)d_in[2];
    const int    Bn   = in_sizes[1];
    float* out_t = (float*)d_out;
    float* out_a = out_t + (size_t)Bn * L_FLAT;
    assoc_sinkhorn_kernel<<<dim3(Bn), dim3(512), 0, stream>>>(aff, ndet, ntrk, out_t, out_a);
}

// Round 3
// 423.291 us; speedup vs baseline: 1.4106x; 1.4106x over previous
//
#include <hip/hip_runtime.h>

// AssociationLayer: masked Sinkhorn (100 iters) + mutual-argmax assignment.
// R9: kill scratch spill. R7/R8 post-mortem: WRITE_SIZE ~390-414 MB sustained
// ~870 GB/s through the WHOLE kernel (not epilogue burst), invariant to
// epilogue restructure -> scratch spill in the loop (KA+KB = 128 persistent
// regs + transients > the 256-reg cap of __launch_bounds__(512,2); rocprof
// showed the 128-arch split). Fix:
//  - KB register panel deleted. K^T lives ONCE in LDS: KT[256 cols][264 slots]
//    bf16 (135 KB; padded stride 528 B = 132 dwords == 4 mod 32 banks ->
//    ds_read_b128 lanes lr/lr+8 alias 2-way = free per m136).
//  - dir2 B-frags are per-iteration ds_read_b128 from KT (16 reads/iter/wave).
//  - KT built inside the KA prologue loop from the SAME row-major aff loads
//    -> the strided col-panel global re-read of aff is gone entirely.
//  - register demand ~150 < 256 cap -> no spill.
//  - epilogue: R7 direct form (simpler; Tbuf can't fit beside KT), col-panel
//    parts (colmax/births) read KT. Identical (u*k)*v mul order on both
//    panels -> bitwise-consistent mutual-argmax equality tests.

#define T_MAX   256
#define L_FLAT  (257 * 257)
#define N_ITERS 100
#define LAMBDA_F 10.0f
#define EPS_F    1e-12f
#define KTP     264    // KT col stride (bf16 slots): 528 B, %16==0 for b128

#define ROR1 0x121
#define ROR2 0x122
#define ROR4 0x124
#define ROR8 0x128

typedef short bf8   __attribute__((ext_vector_type(8)));  // 8 bf16 = 4 VGPRs
typedef float f32x4 __attribute__((ext_vector_type(4)));

template<int CTRL>
__device__ __forceinline__ float dpp_addf(float x) {
    int t = __builtin_amdgcn_update_dpp(0, __float_as_int(x), CTRL, 0xF, 0xF, true);
    return x + __int_as_float(t);
}
__device__ __forceinline__ float swz16_addf(float x) {
    return x + __int_as_float(__builtin_amdgcn_ds_swizzle(__float_as_int(x), 0x401F));
}
__device__ __forceinline__ float swz16_maxf(float x) {
    return fmaxf(x, __int_as_float(__builtin_amdgcn_ds_swizzle(__float_as_int(x), 0x401F)));
}
__device__ __forceinline__ int swz16_ori(int x) {
    return x | __builtin_amdgcn_ds_swizzle(x, 0x401F);
}
__device__ __forceinline__ float fast_rcp(float x) {
#if __has_builtin(__builtin_amdgcn_rcpf)
    return __builtin_amdgcn_rcpf(x);
#else
    return 1.0f / x;
#endif
}
__device__ __forceinline__ unsigned short f2bf(float x) {   // RNE f32->bf16
    unsigned u = __float_as_uint(x);
    return (unsigned short)((u + 0x7FFFu + ((u >> 16) & 1u)) >> 16);
}
__device__ __forceinline__ float bf2f(short s) {            // exact bf16->f32
    return __uint_as_float(((unsigned)(unsigned short)s) << 16);
}

__global__ __launch_bounds__(512, 2) void assoc_sinkhorn_kernel(
    const float* __restrict__ aff,
    const int*   __restrict__ ndet,
    const int*   __restrict__ ntrk,
    float*       __restrict__ out_t,
    float*       __restrict__ out_a)
{
    const int b   = blockIdx.x;
    const int nd  = ndet[b];
    const int nt  = ntrk[b];
    const int tid = threadIdx.x;
    const int w   = tid >> 6;     // wave 0..7
    const int l   = tid & 63;
    const int lr  = l & 15;       // m/n index within 16x16 tile
    const int lk  = l >> 4;       // k-group 0..3

    __shared__ __align__(16) unsigned short KT[256 * KTP];  // 135.2 KB: K^T bf16
    __shared__ __align__(16) unsigned short u_bf[256];
    __shared__ __align__(16) unsigned short v_bf[256];
    __shared__ __align__(16) float u_f[256];
    __shared__ __align__(16) float v_f[256];
    __shared__ __align__(16) float supart[8];
    __shared__ __align__(16) float svpart[8];
    __shared__ __align__(16) float rm_s[256];
    __shared__ __align__(16) float cm_s[256];

    const float ndf = (float)nd;
    const float ntf = (float)nt;

    // ---- prologue: build KA regs (row-panel) + KT in LDS from same loads ----
    bf8 KA[2][8];
    const float* Ab = aff + (size_t)b * (T_MAX * T_MAX);

    #pragma unroll
    for (int a = 0; a < 2; ++a) {
        const int row = 32 * w + 16 * a + lr;
        const bool rv = (row < nt);
        const float* rp = Ab + (size_t)row * T_MAX;
        #pragma unroll
        for (int t = 0; t < 8; ++t) {
            const int c0 = 32 * t + 8 * lk;
            const float4 x0 = *reinterpret_cast<const float4*>(rp + c0);
            const float4 x1 = *reinterpret_cast<const float4*>(rp + c0 + 4);
            const float e[8] = {x0.x, x0.y, x0.z, x0.w, x1.x, x1.y, x1.z, x1.w};
            bf8 kk;
            #pragma unroll
            for (int j = 0; j < 8; ++j) {
                const float val = (rv && (c0 + j) < nd) ? __expf(LAMBDA_F * e[j]) : 0.0f;
                const unsigned short bits = f2bf(val);
                kk[j] = (short)bits;
                KT[(c0 + j) * KTP + row] = bits;   // transposed copy (bitwise same)
            }
            KA[a][t] = kk;
        }
    }

    if (tid < 256) {
        v_bf[tid] = (tid < nd) ? f2bf(1.0f) : (unsigned short)0;
        v_f[tid]  = (tid < nd) ? 1.0f : 0.0f;
    }
    __syncthreads();

    float Sv  = ndf;    // sum of v over valid cols (wave-uniform)
    float vbd = 1.0f;   // v[nd]
    float ubd = 0.0f;   // u[nt]

    const int r_a0 = 32 * w + 4 * lk;        // base row of acc0 quad (a=0)
    const int myc0 = 32 * w + lr;            // dir2 col (cc=0)
    const int myc1 = myc0 + 16;              // dir2 col (cc=1)
    const unsigned short* KT0 = &KT[myc0 * KTP];
    const unsigned short* KT1 = &KT[myc1 * KTP];

    // ---------------- Sinkhorn iterations ----------------
    for (int it = 0; it < N_ITERS; ++it) {
        // ---- dir1: p = K @ v  (row-panel regs, fully in-wave) ----
        bf8 VF[8];
        #pragma unroll
        for (int t = 0; t < 8; ++t)
            VF[t] = *reinterpret_cast<const bf8*>(&v_bf[32 * t + 8 * lk]);

        f32x4 acc0 = {0.0f, 0.0f, 0.0f, 0.0f};
        f32x4 acc1 = {0.0f, 0.0f, 0.0f, 0.0f};
        #pragma unroll
        for (int t = 0; t < 8; ++t) {
            acc0 = __builtin_amdgcn_mfma_f32_16x16x32_bf16(KA[0][t], VF[t], acc0, 0, 0, 0);
            acc1 = __builtin_amdgcn_mfma_f32_16x16x32_bf16(KA[1][t], VF[t], acc1, 0, 0, 0);
        }

        const float ubd_new = ndf * fast_rcp(Sv + vbd + EPS_F);
        const float vbdE = vbd + EPS_F;
        float u8[8];
        #pragma unroll
        for (int q = 0; q < 4; ++q) {
            u8[q]     = ((r_a0 + q)      < nt) ? fast_rcp(acc0[q] + vbdE) : 0.0f;
            u8[4 + q] = ((r_a0 + 16 + q) < nt) ? fast_rcp(acc1[q] + vbdE) : 0.0f;
        }

        // per-wave Sigma(u): values vary over lk only (redundant over lr)
        {
            float su = ((u8[0] + u8[1]) + (u8[2] + u8[3]))
                     + ((u8[4] + u8[5]) + (u8[6] + u8[7]));
            su = swz16_addf(su);
            su += __shfl_xor(su, 32, 64);
            if (l == 0) supart[w] = su;
        }

        // publish u (bf16 for MFMA, f32 for epilogue); writers: lr==0
        if (lr == 0) {
            const unsigned p01 = (unsigned)f2bf(u8[0]) | ((unsigned)f2bf(u8[1]) << 16);
            const unsigned p23 = (unsigned)f2bf(u8[2]) | ((unsigned)f2bf(u8[3]) << 16);
            const unsigned p45 = (unsigned)f2bf(u8[4]) | ((unsigned)f2bf(u8[5]) << 16);
            const unsigned p67 = (unsigned)f2bf(u8[6]) | ((unsigned)f2bf(u8[7]) << 16);
            *reinterpret_cast<uint2*>(&u_bf[r_a0])      = uint2{p01, p23};
            *reinterpret_cast<uint2*>(&u_bf[r_a0 + 16]) = uint2{p45, p67};
            f32x4 uf0 = {u8[0], u8[1], u8[2], u8[3]};
            f32x4 uf1 = {u8[4], u8[5], u8[6], u8[7]};
            *reinterpret_cast<f32x4*>(&u_f[r_a0])      = uf0;
            *reinterpret_cast<f32x4*>(&u_f[r_a0 + 16]) = uf1;
        }
        __syncthreads();   // barrier A: u published

        // ---- dir2: q = K^T @ u  (B-frags streamed from KT in LDS) ----
        f32x4 qa0 = {0.0f, 0.0f, 0.0f, 0.0f};
        f32x4 qa1 = {0.0f, 0.0f, 0.0f, 0.0f};
        #pragma unroll
        for (int t = 0; t < 8; ++t) {
            const bf8 UF = *reinterpret_cast<const bf8*>(&u_bf[32 * t + 8 * lk]);
            const bf8 b0 = *reinterpret_cast<const bf8*>(&KT0[32 * t + 8 * lk]);
            const bf8 b1 = *reinterpret_cast<const bf8*>(&KT1[32 * t + 8 * lk]);
            qa0 = __builtin_amdgcn_mfma_f32_16x16x32_bf16(UF, b0, qa0, 0, 0, 0);
            qa1 = __builtin_amdgcn_mfma_f32_16x16x32_bf16(UF, b1, qa1, 0, 0, 0);
        }

        // Su and vbd update (redundant per wave; supart covered by barrier A)
        const f32x4 sp0 = *reinterpret_cast<const f32x4*>(&supart[0]);
        const f32x4 sp1 = *reinterpret_cast<const f32x4*>(&supart[4]);
        const float Su = ((sp0[0] + sp0[1]) + (sp0[2] + sp0[3]))
                       + ((sp1[0] + sp1[1]) + (sp1[2] + sp1[3]));
        const float vbd_new = ntf * fast_rcp(Su + ubd_new + EPS_F);

        const float ubdE = ubd_new + EPS_F;
        const float v0 = (myc0 < nd) ? fast_rcp(qa0[0] + ubdE) : 0.0f;
        const float v1 = (myc1 < nd) ? fast_rcp(qa1[0] + ubdE) : 0.0f;

        // per-wave Sigma(v): values vary over lr only -> all-DPP row reduce
        {
            float sv = v0 + v1;
            sv = dpp_addf<ROR1>(sv);
            sv = dpp_addf<ROR2>(sv);
            sv = dpp_addf<ROR4>(sv);
            sv = dpp_addf<ROR8>(sv);
            if (l == 0) svpart[w] = sv;
        }
        if (lk == 0) {
            v_bf[myc0] = f2bf(v0);
            v_bf[myc1] = f2bf(v1);
            v_f[myc0]  = v0;
            v_f[myc1]  = v1;
        }
        ubd = ubd_new;
        vbd = vbd_new;
        __syncthreads();   // barrier B: v published

        const f32x4 vp0 = *reinterpret_cast<const f32x4*>(&svpart[0]);
        const f32x4 vp1 = *reinterpret_cast<const f32x4*>(&svpart[4]);
        Sv = ((vp0[0] + vp0[1]) + (vp0[2] + vp0[3]))
           + ((vp1[0] + vp1[1]) + (vp1[2] + vp1[3]));
    }

    // ================= epilogue =================
    // rowmax on row-panel (KA regs), colmax on col-panel (KT LDS).
    // T = (u*k)*v, identical mul order everywhere.
    float rm[2];
    #pragma unroll
    for (int a = 0; a < 2; ++a) {
        const int row = 32 * w + 16 * a + lr;
        const float ur = u_f[row];
        float mm = 0.0f;
        #pragma unroll
        for (int t = 0; t < 8; ++t) {
            const f32x4 va = *reinterpret_cast<const f32x4*>(&v_f[32 * t + 8 * lk]);
            const f32x4 vb = *reinterpret_cast<const f32x4*>(&v_f[32 * t + 8 * lk + 4]);
            const float vj[8] = {va[0], va[1], va[2], va[3], vb[0], vb[1], vb[2], vb[3]};
            #pragma unroll
            for (int j = 0; j < 8; ++j) {
                const float tv = ur * bf2f(KA[a][t][j]) * vj[j];
                mm = fmaxf(mm, tv);
            }
        }
        mm = swz16_maxf(mm);
        mm = fmaxf(mm, __shfl_xor(mm, 32, 64));
        rm[a] = mm;
        if (lk == 0) rm_s[row] = mm;
    }
    float cmv[2];
    #pragma unroll
    for (int c = 0; c < 2; ++c) {
        const int col = (c == 0) ? myc0 : myc1;
        const unsigned short* KTc = (c == 0) ? KT0 : KT1;
        const float vc = v_f[col];
        float mm = 0.0f;
        #pragma unroll
        for (int t = 0; t < 8; ++t) {
            const int rb = 32 * t + 8 * lk;
            const bf8 kb = *reinterpret_cast<const bf8*>(&KTc[rb]);
            const f32x4 ua = *reinterpret_cast<const f32x4*>(&u_f[rb]);
            const f32x4 ub = *reinterpret_cast<const f32x4*>(&u_f[rb + 4]);
            const float uj[8] = {ua[0], ua[1], ua[2], ua[3], ub[0], ub[1], ub[2], ub[3]};
            #pragma unroll
            for (int j = 0; j < 8; ++j) {
                const float tv = uj[j] * bf2f(kb[j]) * vc;
                mm = fmaxf(mm, tv);
            }
        }
        mm = swz16_maxf(mm);
        mm = fmaxf(mm, __shfl_xor(mm, 32, 64));
        cmv[c] = mm;
        if (lk == 0) cm_s[col] = mm;
    }
    __syncthreads();   // rm_s / cm_s published

    float* Ot = out_t + (size_t)b * L_FLAT;
    float* Oa = out_a + (size_t)b * L_FLAT;
    const int stride = nd + 1;

    // births row (col-panel from KT) + corner
    #pragma unroll
    for (int c = 0; c < 2; ++c) {
        const int col = (c == 0) ? myc0 : myc1;
        const unsigned short* KTc = (c == 0) ? KT0 : KT1;
        const float vc = v_f[col];
        const float cmc = cmv[c];
        const bool cv = (col < nd);
        int has = 0;
        #pragma unroll
        for (int t = 0; t < 8; ++t) {
            const int rb = 32 * t + 8 * lk;
            const bf8 kb = *reinterpret_cast<const bf8*>(&KTc[rb]);
            const f32x4 ua = *reinterpret_cast<const f32x4*>(&u_f[rb]);
            const f32x4 ub = *reinterpret_cast<const f32x4*>(&u_f[rb + 4]);
            const f32x4 ra = *reinterpret_cast<const f32x4*>(&rm_s[rb]);
            const f32x4 rb4 = *reinterpret_cast<const f32x4*>(&rm_s[rb + 4]);
            const float uj[8] = {ua[0], ua[1], ua[2], ua[3], ub[0], ub[1], ub[2], ub[3]};
            const float rj[8] = {ra[0], ra[1], ra[2], ra[3], rb4[0], rb4[1], rb4[2], rb4[3]};
            #pragma unroll
            for (int j = 0; j < 8; ++j) {
                const int rowj = rb + j;
                const float tv = uj[j] * bf2f(kb[j]) * vc;
                const bool bit = (rowj < nt) && cv && (tv == rj[j]) && (tv == cmc);
                has |= bit ? 1 : 0;
            }
        }
        has = swz16_ori(has);
        has |= __shfl_xor(has, 32, 64);
        if (lk == 0 && cv) {
            const int kk = nt * stride + col;
            Ot[kk] = ubd * vc;
            Oa[kk] = has ? 0.0f : 1.0f;
        }
    }
    if (tid == 0) {
        const int kk = nt * stride + nd;
        Ot[kk] = ubd * vbd;
        Oa[kk] = 0.0f;
    }

    // interior + deaths (row-panel from KA regs, direct stores)
    #pragma unroll
    for (int a = 0; a < 2; ++a) {
        const int row = 32 * w + 16 * a + lr;
        const float ur = u_f[row];
        const float rma = rm[a];
        const bool rv = (row < nt);
        int has = 0;
        #pragma unroll
        for (int t = 0; t < 8; ++t) {
            const int cb = 32 * t + 8 * lk;
            const f32x4 va  = *reinterpret_cast<const f32x4*>(&v_f[cb]);
            const f32x4 vb  = *reinterpret_cast<const f32x4*>(&v_f[cb + 4]);
            const f32x4 ca  = *reinterpret_cast<const f32x4*>(&cm_s[cb]);
            const f32x4 cb4 = *reinterpret_cast<const f32x4*>(&cm_s[cb + 4]);
            const float vj[8] = {va[0], va[1], va[2], va[3], vb[0], vb[1], vb[2], vb[3]};
            const float cj[8] = {ca[0], ca[1], ca[2], ca[3], cb4[0], cb4[1], cb4[2], cb4[3]};
            #pragma unroll
            for (int j = 0; j < 8; ++j) {
                const int colj = cb + j;
                const float tv = ur * bf2f(KA[a][t][j]) * vj[j];
                const bool bit = rv && (colj < nd) && (tv == rma) && (tv == cj[j]);
                has |= bit ? 1 : 0;
                if (rv && colj < nd) {
                    Ot[row * stride + colj] = tv;
                    Oa[row * stride + colj] = bit ? 1.0f : 0.0f;
                }
            }
        }
        has = swz16_ori(has);
        has |= __shfl_xor(has, 32, 64);
        if (lk == 0 && rv) {
            const int kk = row * stride + nd;
            Ot[kk] = ur * vbd;
            Oa[kk] = has ? 0.0f : 1.0f;
        }
    }

    // zero-fill padding [length, L_FLAT)
    const int length = (nt + 1) * stride;
    for (int k = length + tid; k < L_FLAT; k += 512) {
        Ot[k] = 0.0f;
        Oa[k] = 0.0f;
    }
}

extern "C" void kernel_launch(void* const* d_in, const int* in_sizes, int n_in,
                              void* d_out, int out_size, void* d_ws, size_t ws_size,
                              hipStream_t stream)
{
    const float* aff  = (const float*)d_in[0];
    const int*   ndet = (const int*)d_in[1];
    const int*   ntrk = (const int*)d_in[2];
    const int    Bn   = in_sizes[1];
    float* out_t = (float*)d_out;
    float* out_a = out_t + (size_t)Bn * L_FLAT;
    assoc_sinkhorn_kernel<<<dim3(Bn), dim3(512), 0, stream>>>(aff, ndet, ntrk, out_t, out_a);
}